// Round 1
// baseline (485.527 us; speedup 1.0000x reference)
//
#include <hip/hip_runtime.h>
#include <stdint.h>

#define T_TOK 4096
#define Hd    1024
#define Id    512
#define NE    16
#define NSLOT 32
#define TOPK  4
#define CAPR  (T_TOK*TOPK)

typedef __bf16 bf16x8 __attribute__((ext_vector_type(8)));
typedef float  floatx4 __attribute__((ext_vector_type(4)));

static __device__ __forceinline__ unsigned short f2bf(float f){
  unsigned int u = __float_as_uint(f);
  u = u + 0x7fffu + ((u >> 16) & 1u);
  return (unsigned short)(u >> 16);
}

static __device__ __forceinline__ void load_lds16(const void* g, void* l){
  __builtin_amdgcn_global_load_lds((const __attribute__((address_space(1))) void*)g,
                                   (__attribute__((address_space(3))) void*)l, 16, 0, 0);
}

// ---------------- x -> bf16 ----------------
__global__ __launch_bounds__(256) void cvt_x_kernel(const float* __restrict__ x,
                                                    unsigned short* __restrict__ xb){
  int i = blockIdx.x * 256 + threadIdx.x;        // float4 index, T*H/4 total
  float4 v = ((const float4*)x)[i];
  ushort4 o;
  o.x = f2bf(v.x); o.y = f2bf(v.y); o.z = f2bf(v.z); o.w = f2bf(v.w);
  ((ushort4*)xb)[i] = o;
}

// ---------------- W [e][R][C] fp32 -> Wt [e][C][R] bf16 ----------------
__global__ __launch_bounds__(256) void transpose_cvt_kernel(
    const float* __restrict__ src, unsigned short* __restrict__ dst, int R, int C){
  __shared__ float tile[64][65];
  const int e = blockIdx.z;
  const int c0 = blockIdx.x * 64;
  const int r0 = blockIdx.y * 64;
  const float* s = src + (size_t)e * R * C;
  unsigned short* d = dst + (size_t)e * R * C;
  const int lr = threadIdx.x >> 4;        // 0..15
  const int lc = (threadIdx.x & 15) * 4;  // 0..60
  #pragma unroll
  for (int p = 0; p < 4; ++p){
    int r = p*16 + lr;
    float4 v = *(const float4*)(s + (size_t)(r0 + r)*C + c0 + lc);
    tile[r][lc+0] = v.x; tile[r][lc+1] = v.y; tile[r][lc+2] = v.z; tile[r][lc+3] = v.w;
  }
  __syncthreads();
  #pragma unroll
  for (int p = 0; p < 4; ++p){
    int c = p*16 + lr;
    ushort4 o;
    o.x = f2bf(tile[lc+0][c]); o.y = f2bf(tile[lc+1][c]);
    o.z = f2bf(tile[lc+2][c]); o.w = f2bf(tile[lc+3][c]);
    *(ushort4*)(d + (size_t)(c0 + c)*R + r0 + lc) = o;
  }
}

// ---------------- fp32 router logits, split-K with atomics ----------------
__global__ __launch_bounds__(256) void logits_kernel(const float* __restrict__ x,
    const float* __restrict__ rw, float* __restrict__ logits){
  __shared__ float srw[NSLOT][260];          // pad 260: spreads banks for strided reads
  const int kc = blockIdx.y * 256;
  const int tid = threadIdx.x;
  #pragma unroll
  for (int p = 0; p < 8; ++p){
    int idx = tid + p*256;                   // float4 units over 32x256
    int s = idx >> 6;
    int c = (idx & 63) << 2;
    float4 v = *(const float4*)(rw + (size_t)s*Hd + kc + c);
    *(float4*)&srw[s][c] = v;
  }
  __syncthreads();
  const int tg = tid >> 3;                   // 0..31 -> 4 tokens each
  const int sg = tid & 7;                    // 0..7  -> 4 slots each
  const int t0 = blockIdx.x * 128 + tg * 4;
  const int s0 = sg * 4;
  float acc[4][4] = {};
  for (int k = 0; k < 256; k += 4){
    float4 r0 = *(const float4*)&srw[s0+0][k];
    float4 r1 = *(const float4*)&srw[s0+1][k];
    float4 r2 = *(const float4*)&srw[s0+2][k];
    float4 r3 = *(const float4*)&srw[s0+3][k];
    #pragma unroll
    for (int tt = 0; tt < 4; ++tt){
      float4 xv = *(const float4*)(x + (size_t)(t0+tt)*Hd + kc + k);
      acc[tt][0] += xv.x*r0.x + xv.y*r0.y + xv.z*r0.z + xv.w*r0.w;
      acc[tt][1] += xv.x*r1.x + xv.y*r1.y + xv.z*r1.z + xv.w*r1.w;
      acc[tt][2] += xv.x*r2.x + xv.y*r2.y + xv.z*r2.z + xv.w*r2.w;
      acc[tt][3] += xv.x*r3.x + xv.y*r3.y + xv.z*r3.z + xv.w*r3.w;
    }
  }
  #pragma unroll
  for (int tt = 0; tt < 4; ++tt)
    #pragma unroll
    for (int s = 0; s < 4; ++s)
      atomicAdd(&logits[(size_t)(t0+tt)*NSLOT + s0 + s], acc[tt][s]);
}

// ---------------- softmax + bias + top-4 ----------------
__global__ __launch_bounds__(256) void topk_kernel(
    const float* __restrict__ logits, const float* __restrict__ bias,
    int* __restrict__ counts, int* __restrict__ tkid, float* __restrict__ tkw,
    float* __restrict__ zero_w){
  int t = blockIdx.x * 256 + threadIdx.x;
  float sc[32], bsc[32];
  #pragma unroll
  for (int i = 0; i < 32; i += 4){
    float4 v = *(const float4*)(logits + (size_t)t*NSLOT + i);
    sc[i] = v.x; sc[i+1] = v.y; sc[i+2] = v.z; sc[i+3] = v.w;
  }
  float mx = sc[0];
  #pragma unroll
  for (int i = 1; i < 32; ++i) mx = fmaxf(mx, sc[i]);
  float sum = 0.f;
  #pragma unroll
  for (int i = 0; i < 32; ++i){ sc[i] = __expf(sc[i]-mx); sum += sc[i]; }
  float inv = 1.f / sum;
  #pragma unroll
  for (int i = 0; i < 32; ++i){ sc[i] *= inv; bsc[i] = sc[i] + bias[i]; }
  unsigned int chosen = 0;
  float zw = 0.f;
  #pragma unroll
  for (int k = 0; k < TOPK; ++k){
    float bv = -1e30f, bw = 0.f; int best = 0;
    #pragma unroll
    for (int i = 0; i < 32; ++i){
      float v = ((chosen >> i) & 1u) ? -1e30f : bsc[i];
      if (v > bv){ bv = v; best = i; bw = sc[i]; }   // strict > : ties pick lowest idx (matches lax.top_k)
    }
    chosen |= (1u << best);
    tkid[t*TOPK + k] = best;
    tkw[t*TOPK + k]  = bw;
    if (best < NE) atomicAdd(&counts[best], 1);
    else zw += bw;
  }
  zero_w[t] = zw;
}

// ---------------- offsets scan (tiny) ----------------
__global__ void offsets_kernel(const int* __restrict__ counts,
                               int* __restrict__ offsets, int* __restrict__ cursors){
  if (threadIdx.x == 0){
    int acc = 0;
    for (int e = 0; e < NE; ++e){ offsets[e] = acc; acc += counts[e]; }
    offsets[NE] = acc;
  }
  if (threadIdx.x < NE) cursors[threadIdx.x] = 0;
}

// ---------------- build compact per-expert row lists ----------------
__global__ __launch_bounds__(256) void build_kernel(
    const int* __restrict__ tkid, const float* __restrict__ tkw,
    const int* __restrict__ offsets, int* __restrict__ cursors,
    int* __restrict__ rowmap, float* __restrict__ roww){
  int i = blockIdx.x * 256 + threadIdx.x;   // 0..CAPR-1
  int id = tkid[i];
  if (id < NE){
    int pos = atomicAdd(&cursors[id], 1);
    int row = offsets[id] + pos;
    rowmap[row] = i >> 2;                    // token
    roww[row]   = tkw[i];
  }
}

// ---------------- out = zero_w * x ----------------
__global__ __launch_bounds__(256) void outinit_kernel(const float* __restrict__ x,
    const float* __restrict__ zw, float* __restrict__ out){
  int i = blockIdx.x * 256 + threadIdx.x;    // float4 index
  float s = zw[i >> 8];                      // i*4/1024
  float4 v = ((const float4*)x)[i];
  float4 o; o.x = v.x*s; o.y = v.y*s; o.z = v.z*s; o.w = v.w*s;
  ((float4*)out)[i] = o;
}

// ---------------- fused gate+up GEMM + SwiGLU (128x128 tile, bf16 MFMA) ----------------
__global__ __launch_bounds__(256, 2) void gateup_kernel(
    const unsigned short* __restrict__ xb,
    const unsigned short* __restrict__ wgb,   // [e][i][h] bf16 (transposed)
    const unsigned short* __restrict__ wub,
    const int* __restrict__ offsets,
    const int* __restrict__ rowmap,
    const float* __restrict__ roww,
    unsigned short* __restrict__ act){
  const int e   = blockIdx.z;
  const int off = offsets[e];
  const int ne  = offsets[e+1] - off;
  const int m0  = blockIdx.x * 128;
  if (m0 >= ne) return;
  const int n0  = blockIdx.y * 128;

  __shared__ unsigned short sA [128*32];
  __shared__ unsigned short sBg[128*32];
  __shared__ unsigned short sBu[128*32];
  __shared__ int sT[128];

  const int tid  = threadIdx.x;
  const int lane = tid & 63;
  const int wid  = tid >> 6;

  if (tid < 128){
    int r = m0 + tid;
    sT[tid] = rowmap[off + ((r < ne) ? r : 0)];
  }
  __syncthreads();

  const int r_in = lane >> 2;   // 0..15 rows within 1KB issue
  const int seg  = lane & 3;    // 0..3  16B segments within 64B row

  floatx4 accg[4][4], accu[4][4];
  #pragma unroll
  for (int i = 0; i < 4; ++i)
    #pragma unroll
    for (int j = 0; j < 4; ++j){
      floatx4 z = {0.f,0.f,0.f,0.f};
      accg[i][j] = z; accu[i][j] = z;
    }

  const int wm = (wid & 1) * 64;
  const int wn = (wid >> 1) * 64;
  const int fm = lane & 15;
  const int fq = lane >> 4;
  const size_t wbase = (size_t)e * Id * Hd;

  for (int k0 = 0; k0 < Hd; k0 += 32){
    #pragma unroll
    for (int p = 0; p < 2; ++p){
      int rt = wid*32 + p*16 + r_in;
      int t  = sT[rt];
      load_lds16(xb + (size_t)t*Hd + (k0 + seg*8),              sA  + (wid*32 + p*16)*32);
      load_lds16(wgb + wbase + (size_t)(n0 + rt)*Hd + (k0 + seg*8), sBg + (wid*32 + p*16)*32);
      load_lds16(wub + wbase + (size_t)(n0 + rt)*Hd + (k0 + seg*8), sBu + (wid*32 + p*16)*32);
    }
    __syncthreads();
    bf16x8 av[4], bgv[4], buv[4];
    #pragma unroll
    for (int i = 0; i < 4; ++i)
      av[i] = *(const bf16x8*)(sA + (wm + i*16 + fm)*32 + fq*8);
    #pragma unroll
    for (int j = 0; j < 4; ++j){
      bgv[j] = *(const bf16x8*)(sBg + (wn + j*16 + fm)*32 + fq*8);
      buv[j] = *(const bf16x8*)(sBu + (wn + j*16 + fm)*32 + fq*8);
    }
    #pragma unroll
    for (int i = 0; i < 4; ++i)
      #pragma unroll
      for (int j = 0; j < 4; ++j){
        accg[i][j] = __builtin_amdgcn_mfma_f32_16x16x32_bf16(av[i], bgv[j], accg[i][j], 0, 0, 0);
        accu[i][j] = __builtin_amdgcn_mfma_f32_16x16x32_bf16(av[i], buv[j], accu[i][j], 0, 0, 0);
      }
    __syncthreads();
  }

  #pragma unroll
  for (int i = 0; i < 4; ++i){
    #pragma unroll
    for (int r = 0; r < 4; ++r){
      int row = wm + i*16 + fq*4 + r;        // C layout: row=(lane>>4)*4+reg, col=lane&15
      if (m0 + row < ne){
        float w = roww[off + m0 + row];
        size_t rb = (size_t)(off + m0 + row) * Id + n0;
        #pragma unroll
        for (int j = 0; j < 4; ++j){
          float g = accg[i][j][r];
          float u = accu[i][j][r];
          float a = (g / (1.f + __expf(-g))) * u * w;   // silu(g)*u, routing weight folded
          act[rb + wn + j*16 + fm] = f2bf(a);
        }
      }
    }
  }
}

// ---------------- down GEMM + atomic scatter ----------------
__global__ __launch_bounds__(256, 2) void down_kernel(
    const unsigned short* __restrict__ act,
    const unsigned short* __restrict__ wdb,   // [e][h][i] bf16 (transposed)
    const int* __restrict__ offsets,
    const int* __restrict__ rowmap,
    float* __restrict__ out){
  const int e   = blockIdx.z;
  const int off = offsets[e];
  const int ne  = offsets[e+1] - off;
  const int m0  = blockIdx.x * 128;
  if (m0 >= ne) return;
  const int n0  = blockIdx.y * 128;

  __shared__ unsigned short sA[128*32];
  __shared__ unsigned short sB[128*32];
  __shared__ int sT[128];

  const int tid  = threadIdx.x;
  const int lane = tid & 63;
  const int wid  = tid >> 6;
  if (tid < 128){
    int r = m0 + tid;
    sT[tid] = (r < ne) ? rowmap[off + r] : 0;
  }

  const int r_in = lane >> 2, seg = lane & 3;
  floatx4 acc[4][4];
  #pragma unroll
  for (int i = 0; i < 4; ++i)
    #pragma unroll
    for (int j = 0; j < 4; ++j){ floatx4 z = {0.f,0.f,0.f,0.f}; acc[i][j] = z; }

  const int wm = (wid & 1) * 64, wn = (wid >> 1) * 64;
  const int fm = lane & 15, fq = lane >> 4;
  const size_t wbase = (size_t)e * Hd * Id;

  for (int k0 = 0; k0 < Id; k0 += 32){
    #pragma unroll
    for (int p = 0; p < 2; ++p){
      int rt = wid*32 + p*16 + r_in;
      int gr = off + ((m0 + rt < ne) ? (m0 + rt) : 0);
      load_lds16(act + (size_t)gr*Id + (k0 + seg*8),               sA + (wid*32 + p*16)*32);
      load_lds16(wdb + wbase + (size_t)(n0 + rt)*Id + (k0 + seg*8), sB + (wid*32 + p*16)*32);
    }
    __syncthreads();
    bf16x8 av[4], bv[4];
    #pragma unroll
    for (int i = 0; i < 4; ++i) av[i] = *(const bf16x8*)(sA + (wm + i*16 + fm)*32 + fq*8);
    #pragma unroll
    for (int j = 0; j < 4; ++j) bv[j] = *(const bf16x8*)(sB + (wn + j*16 + fm)*32 + fq*8);
    #pragma unroll
    for (int i = 0; i < 4; ++i)
      #pragma unroll
      for (int j = 0; j < 4; ++j)
        acc[i][j] = __builtin_amdgcn_mfma_f32_16x16x32_bf16(av[i], bv[j], acc[i][j], 0, 0, 0);
    __syncthreads();
  }

  #pragma unroll
  for (int i = 0; i < 4; ++i){
    #pragma unroll
    for (int r = 0; r < 4; ++r){
      int row = wm + i*16 + fq*4 + r;
      if (m0 + row < ne){
        int t = sT[row];
        #pragma unroll
        for (int j = 0; j < 4; ++j)
          atomicAdd(&out[(size_t)t*Hd + n0 + wn + j*16 + fm], acc[i][j][r]);
      }
    }
  }
}

// =================================================================
extern "C" void kernel_launch(void* const* d_in, const int* in_sizes, int n_in,
                              void* d_out, int out_size, void* d_ws, size_t ws_size,
                              hipStream_t stream){
  (void)in_sizes; (void)n_in; (void)out_size; (void)ws_size;
  const float* x    = (const float*)d_in[0];
  const float* rw   = (const float*)d_in[1];
  const float* bias = (const float*)d_in[2];
  const float* wg   = (const float*)d_in[3];
  const float* wu   = (const float*)d_in[4];
  const float* wd   = (const float*)d_in[5];
  float* out = (float*)d_out;

  char* ws = (char*)d_ws;
  const size_t WSZ = (size_t)NE * Id * Hd * 2;      // 16 MiB per weight array (bf16)
  unsigned short* wgb = (unsigned short*)(ws);
  unsigned short* wub = (unsigned short*)(ws + WSZ);
  unsigned short* wdb = (unsigned short*)(ws + 2*WSZ);
  unsigned short* xb  = (unsigned short*)(ws + 3*WSZ);
  unsigned short* act = (unsigned short*)(ws + 3*WSZ + (size_t)T_TOK*Hd*2);
  char* misc = ws + 3*WSZ + (size_t)T_TOK*Hd*2 + (size_t)CAPR*Id*2;

  const size_t LOGB = (size_t)T_TOK * NSLOT * 4;    // 512 KiB
  float* logits = (float*)misc;
  int*   counts  = (int*)(misc + LOGB);
  int*   cursors = counts + 16;
  int*   offsets = cursors + 16;                    // 17 ints, within 256B pad
  char* p2 = misc + LOGB + 256;
  int*   tkid   = (int*)p2;                         p2 += (size_t)T_TOK*TOPK*4;
  float* tkw    = (float*)p2;                       p2 += (size_t)T_TOK*TOPK*4;
  float* zerow  = (float*)p2;                       p2 += (size_t)T_TOK*4;
  int*   rowmap = (int*)p2;                         p2 += (size_t)CAPR*4;
  float* roww   = (float*)p2;

  // zero logits + counts/cursors/offsets
  hipMemsetAsync(misc, 0, LOGB + 256, stream);

  // bf16 conversions / transposes
  cvt_x_kernel<<<T_TOK*Hd/4/256, 256, 0, stream>>>(x, xb);
  transpose_cvt_kernel<<<dim3(Id/64, Hd/64, NE), 256, 0, stream>>>(wg, wgb, Hd, Id);
  transpose_cvt_kernel<<<dim3(Id/64, Hd/64, NE), 256, 0, stream>>>(wu, wub, Hd, Id);
  transpose_cvt_kernel<<<dim3(Hd/64, Id/64, NE), 256, 0, stream>>>(wd, wdb, Id, Hd);

  // router (fp32)
  logits_kernel<<<dim3(T_TOK/128, Hd/256), 256, 0, stream>>>(x, rw, logits);
  topk_kernel<<<T_TOK/256, 256, 0, stream>>>(logits, bias, counts, tkid, tkw, zerow);
  offsets_kernel<<<1, 64, 0, stream>>>(counts, offsets, cursors);
  build_kernel<<<CAPR/256, 256, 0, stream>>>(tkid, tkw, offsets, cursors, rowmap, roww);

  // identity (zero-expert) term
  outinit_kernel<<<T_TOK*Hd/4/256, 256, 0, stream>>>(x, zerow, out);

  // grouped expert GEMMs
  gateup_kernel<<<dim3(T_TOK/128, Id/128, NE), 256, 0, stream>>>(
      xb, wgb, wub, offsets, rowmap, roww, act);
  down_kernel<<<dim3(T_TOK/128, Hd/128, NE), 256, 0, stream>>>(
      act, wdb, offsets, rowmap, out);
}

// Round 2
// 319.753 us; speedup vs baseline: 1.5184x; 1.5184x over previous
//
#include <hip/hip_runtime.h>
#include <stdint.h>

#define T_TOK 4096
#define Hd    1024
#define Id    512
#define NE    16
#define NSLOT 32
#define TOPK  4
#define CAPR  (T_TOK*TOPK)
#define MAXTILES 144   // sum ceil(ne/128) <= 16384/128 + 16 = 144

typedef __bf16 bf16x8 __attribute__((ext_vector_type(8)));
typedef float  floatx4 __attribute__((ext_vector_type(4)));

#define WAIT_VM(n) asm volatile("s_waitcnt vmcnt(" #n ")" ::: "memory")

static __device__ __forceinline__ void wg_barrier(){
  asm volatile("" ::: "memory");
  __builtin_amdgcn_s_barrier();
  asm volatile("" ::: "memory");
}

static __device__ __forceinline__ unsigned short f2bf(float f){
  unsigned int u = __float_as_uint(f);
  u = u + 0x7fffu + ((u >> 16) & 1u);
  return (unsigned short)(u >> 16);
}

static __device__ __forceinline__ void load_lds16(const void* g, void* l){
  __builtin_amdgcn_global_load_lds((const __attribute__((address_space(1))) void*)g,
                                   (__attribute__((address_space(3))) void*)l, 16, 0, 0);
}

// ---------------- x -> bf16 ----------------
__global__ __launch_bounds__(256) void cvt_x_kernel(const float* __restrict__ x,
                                                    unsigned short* __restrict__ xb){
  int i = blockIdx.x * 256 + threadIdx.x;
  float4 v = ((const float4*)x)[i];
  ushort4 o;
  o.x = f2bf(v.x); o.y = f2bf(v.y); o.z = f2bf(v.z); o.w = f2bf(v.w);
  ((ushort4*)xb)[i] = o;
}

// ---------------- W [e][R][C] fp32 -> Wt [e][C][R] bf16 ----------------
__global__ __launch_bounds__(256) void transpose_cvt_kernel(
    const float* __restrict__ src, unsigned short* __restrict__ dst, int R, int C){
  __shared__ float tile[64][65];
  const int e = blockIdx.z;
  const int c0 = blockIdx.x * 64;
  const int r0 = blockIdx.y * 64;
  const float* s = src + (size_t)e * R * C;
  unsigned short* d = dst + (size_t)e * R * C;
  const int lr = threadIdx.x >> 4;
  const int lc = (threadIdx.x & 15) * 4;
  #pragma unroll
  for (int p = 0; p < 4; ++p){
    int r = p*16 + lr;
    float4 v = *(const float4*)(s + (size_t)(r0 + r)*C + c0 + lc);
    tile[r][lc+0] = v.x; tile[r][lc+1] = v.y; tile[r][lc+2] = v.z; tile[r][lc+3] = v.w;
  }
  __syncthreads();
  #pragma unroll
  for (int p = 0; p < 4; ++p){
    int c = p*16 + lr;
    ushort4 o;
    o.x = f2bf(tile[lc+0][c]); o.y = f2bf(tile[lc+1][c]);
    o.z = f2bf(tile[lc+2][c]); o.w = f2bf(tile[lc+3][c]);
    *(ushort4*)(d + (size_t)(c0 + c)*R + r0 + lc) = o;
  }
}

// ---------------- fp32 router logits, split-K with atomics ----------------
__global__ __launch_bounds__(256) void logits_kernel(const float* __restrict__ x,
    const float* __restrict__ rw, float* __restrict__ logits){
  __shared__ float srw[NSLOT][260];
  const int kc = blockIdx.y * 256;
  const int tid = threadIdx.x;
  #pragma unroll
  for (int p = 0; p < 8; ++p){
    int idx = tid + p*256;
    int s = idx >> 6;
    int c = (idx & 63) << 2;
    float4 v = *(const float4*)(rw + (size_t)s*Hd + kc + c);
    *(float4*)&srw[s][c] = v;
  }
  __syncthreads();
  const int tg = tid >> 3;
  const int sg = tid & 7;
  const int t0 = blockIdx.x * 128 + tg * 4;
  const int s0 = sg * 4;
  float acc[4][4] = {};
  for (int k = 0; k < 256; k += 4){
    float4 r0 = *(const float4*)&srw[s0+0][k];
    float4 r1 = *(const float4*)&srw[s0+1][k];
    float4 r2 = *(const float4*)&srw[s0+2][k];
    float4 r3 = *(const float4*)&srw[s0+3][k];
    #pragma unroll
    for (int tt = 0; tt < 4; ++tt){
      float4 xv = *(const float4*)(x + (size_t)(t0+tt)*Hd + kc + k);
      acc[tt][0] += xv.x*r0.x + xv.y*r0.y + xv.z*r0.z + xv.w*r0.w;
      acc[tt][1] += xv.x*r1.x + xv.y*r1.y + xv.z*r1.z + xv.w*r1.w;
      acc[tt][2] += xv.x*r2.x + xv.y*r2.y + xv.z*r2.z + xv.w*r2.w;
      acc[tt][3] += xv.x*r3.x + xv.y*r3.y + xv.z*r3.z + xv.w*r3.w;
    }
  }
  #pragma unroll
  for (int tt = 0; tt < 4; ++tt)
    #pragma unroll
    for (int s = 0; s < 4; ++s)
      atomicAdd(&logits[(size_t)(t0+tt)*NSLOT + s0 + s], acc[tt][s]);
}

// ---------------- softmax + bias + top-4 ----------------
__global__ __launch_bounds__(256) void topk_kernel(
    const float* __restrict__ logits, const float* __restrict__ bias,
    int* __restrict__ counts, int* __restrict__ tkid, float* __restrict__ tkw,
    float* __restrict__ zero_w){
  int t = blockIdx.x * 256 + threadIdx.x;
  float sc[32], bsc[32];
  #pragma unroll
  for (int i = 0; i < 32; i += 4){
    float4 v = *(const float4*)(logits + (size_t)t*NSLOT + i);
    sc[i] = v.x; sc[i+1] = v.y; sc[i+2] = v.z; sc[i+3] = v.w;
  }
  float mx = sc[0];
  #pragma unroll
  for (int i = 1; i < 32; ++i) mx = fmaxf(mx, sc[i]);
  float sum = 0.f;
  #pragma unroll
  for (int i = 0; i < 32; ++i){ sc[i] = __expf(sc[i]-mx); sum += sc[i]; }
  float inv = 1.f / sum;
  #pragma unroll
  for (int i = 0; i < 32; ++i){ sc[i] *= inv; bsc[i] = sc[i] + bias[i]; }
  unsigned int chosen = 0;
  float zw = 0.f;
  #pragma unroll
  for (int k = 0; k < TOPK; ++k){
    float bv = -1e30f, bw = 0.f; int best = 0;
    #pragma unroll
    for (int i = 0; i < 32; ++i){
      float v = ((chosen >> i) & 1u) ? -1e30f : bsc[i];
      if (v > bv){ bv = v; best = i; bw = sc[i]; }
    }
    chosen |= (1u << best);
    tkid[t*TOPK + k] = best;
    tkw[t*TOPK + k]  = bw;
    if (best < NE) atomicAdd(&counts[best], 1);
    else zw += bw;
  }
  zero_w[t] = zw;
}

// ---------------- offsets scan + tile list (tiny) ----------------
__global__ void offsets_kernel(const int* __restrict__ counts,
                               int* __restrict__ offsets, int* __restrict__ cursors,
                               int* __restrict__ tilelist, int* __restrict__ ntiles){
  if (threadIdx.x == 0){
    int acc = 0;
    for (int e = 0; e < NE; ++e){ offsets[e] = acc; acc += counts[e]; }
    offsets[NE] = acc;
    int n = 0;
    for (int e = 0; e < NE; ++e){
      int ne = counts[e];
      for (int m = 0; m*128 < ne; ++m) tilelist[n++] = (e << 16) | m;
    }
    ntiles[0] = n;
  }
  if (threadIdx.x < NE) cursors[threadIdx.x] = 0;
}

// ---------------- build compact per-expert row lists ----------------
__global__ __launch_bounds__(256) void build_kernel(
    const int* __restrict__ tkid, const float* __restrict__ tkw,
    const int* __restrict__ offsets, int* __restrict__ cursors,
    int* __restrict__ rowmap, float* __restrict__ roww){
  int i = blockIdx.x * 256 + threadIdx.x;
  int id = tkid[i];
  if (id < NE){
    int pos = atomicAdd(&cursors[id], 1);
    int row = offsets[id] + pos;
    rowmap[row] = i >> 2;
    roww[row]   = tkw[i];
  }
}

// ---------------- out = zero_w * x ----------------
__global__ __launch_bounds__(256) void outinit_kernel(const float* __restrict__ x,
    const float* __restrict__ zw, float* __restrict__ out){
  int i = blockIdx.x * 256 + threadIdx.x;
  float s = zw[i >> 8];
  float4 v = ((const float4*)x)[i];
  float4 o; o.x = v.x*s; o.y = v.y*s; o.z = v.z*s; o.w = v.w*s;
  ((float4*)out)[i] = o;
}

// ---------------- fused gate+up GEMM + SwiGLU (128x128, dbuf, tile-list) ----------------
__global__ __launch_bounds__(256, 2) void gateup_kernel(
    const unsigned short* __restrict__ xb,
    const unsigned short* __restrict__ wgb,
    const unsigned short* __restrict__ wub,
    const int* __restrict__ offsets,
    const int* __restrict__ rowmap,
    const float* __restrict__ roww,
    const int* __restrict__ tilelist,
    const int* __restrict__ ntiles,
    unsigned short* __restrict__ act){
  const int b = blockIdx.x;
  const int tile = b >> 2;
  if (tile >= ntiles[0]) return;
  const int packed = tilelist[tile];
  const int e  = packed >> 16;
  const int m0 = (packed & 0xffff) * 128;
  const int n0 = (b & 3) * 128;
  const int off = offsets[e];
  const int ne  = offsets[e+1] - off;

  __shared__ unsigned short sA [2][128*32];
  __shared__ unsigned short sBg[2][128*32];
  __shared__ unsigned short sBu[2][128*32];
  __shared__ int sT[128];

  const int tid  = threadIdx.x;
  const int lane = tid & 63;
  const int wid  = tid >> 6;

  if (tid < 128){
    int r = m0 + tid;
    sT[tid] = rowmap[off + ((r < ne) ? r : 0)];
  }
  __syncthreads();

  const int r_in = lane >> 2;
  const int seg  = lane & 3;
  const int rt0  = wid*32 + r_in;
  const int rt1  = rt0 + 16;
  const size_t wbase = (size_t)e * Id * Hd;

  // loop-invariant global pointers (k added per iter)
  const unsigned short* pA0 = xb + (size_t)sT[rt0]*Hd + seg*8;
  const unsigned short* pA1 = xb + (size_t)sT[rt1]*Hd + seg*8;
  const unsigned short* pG0 = wgb + wbase + (size_t)(n0+rt0)*Hd + seg*8;
  const unsigned short* pG1 = wgb + wbase + (size_t)(n0+rt1)*Hd + seg*8;
  const unsigned short* pU0 = wub + wbase + (size_t)(n0+rt0)*Hd + seg*8;
  const unsigned short* pU1 = wub + wbase + (size_t)(n0+rt1)*Hd + seg*8;
  const int dA0 = wid*1024;        // ushort offset of this wave's p=0 region
  const int dA1 = wid*1024 + 512;  // p=1 region

  floatx4 accg[4][4], accu[4][4];
  #pragma unroll
  for (int i = 0; i < 4; ++i)
    #pragma unroll
    for (int j = 0; j < 4; ++j){
      floatx4 z = {0.f,0.f,0.f,0.f};
      accg[i][j] = z; accu[i][j] = z;
    }

  const int wm = (wid & 1) * 64;
  const int wn = (wid >> 1) * 64;
  const int fm = lane & 15;
  const int fq = lane >> 4;

  // prologue: tile 0 into buf 0
  load_lds16(pA0, &sA[0][dA0]);  load_lds16(pA1, &sA[0][dA1]);
  load_lds16(pG0, &sBg[0][dA0]); load_lds16(pG1, &sBg[0][dA1]);
  load_lds16(pU0, &sBu[0][dA0]); load_lds16(pU1, &sBu[0][dA1]);

  #pragma unroll 2
  for (int kit = 0; kit < 32; ++kit){
    const int cur = kit & 1;
    if (kit < 31){
      const int nk = (kit+1)*32;
      const int nb = 1 - cur;
      load_lds16(pA0 + nk, &sA[nb][dA0]);  load_lds16(pA1 + nk, &sA[nb][dA1]);
      load_lds16(pG0 + nk, &sBg[nb][dA0]); load_lds16(pG1 + nk, &sBg[nb][dA1]);
      load_lds16(pU0 + nk, &sBu[nb][dA0]); load_lds16(pU1 + nk, &sBu[nb][dA1]);
      WAIT_VM(6);                 // tile-kit loads done; prefetch stays in flight
    } else {
      WAIT_VM(0);
    }
    wg_barrier();
    bf16x8 av[4], bgv[4], buv[4];
    #pragma unroll
    for (int i = 0; i < 4; ++i)
      av[i] = *(const bf16x8*)(&sA[cur][(wm + i*16 + fm)*32 + fq*8]);
    #pragma unroll
    for (int j = 0; j < 4; ++j){
      bgv[j] = *(const bf16x8*)(&sBg[cur][(wn + j*16 + fm)*32 + fq*8]);
      buv[j] = *(const bf16x8*)(&sBu[cur][(wn + j*16 + fm)*32 + fq*8]);
    }
    #pragma unroll
    for (int i = 0; i < 4; ++i)
      #pragma unroll
      for (int j = 0; j < 4; ++j){
        accg[i][j] = __builtin_amdgcn_mfma_f32_16x16x32_bf16(av[i], bgv[j], accg[i][j], 0, 0, 0);
        accu[i][j] = __builtin_amdgcn_mfma_f32_16x16x32_bf16(av[i], buv[j], accu[i][j], 0, 0, 0);
      }
    wg_barrier();                 // readers done before next iter overwrites buf
  }

  #pragma unroll
  for (int i = 0; i < 4; ++i){
    #pragma unroll
    for (int r = 0; r < 4; ++r){
      int row = wm + i*16 + fq*4 + r;
      if (m0 + row < ne){
        float w = roww[off + m0 + row];
        size_t rb = (size_t)(off + m0 + row) * Id + n0;
        #pragma unroll
        for (int j = 0; j < 4; ++j){
          float g = accg[i][j][r];
          float u = accu[i][j][r];
          float a = (g / (1.f + __expf(-g))) * u * w;
          act[rb + wn + j*16 + fm] = f2bf(a);
        }
      }
    }
  }
}

// ---------------- down GEMM + atomic scatter (dbuf, tile-list) ----------------
__global__ __launch_bounds__(256, 2) void down_kernel(
    const unsigned short* __restrict__ act,
    const unsigned short* __restrict__ wdb,
    const int* __restrict__ offsets,
    const int* __restrict__ rowmap,
    const int* __restrict__ tilelist,
    const int* __restrict__ ntiles,
    float* __restrict__ out){
  const int b = blockIdx.x;
  const int tile = b >> 3;
  if (tile >= ntiles[0]) return;
  const int packed = tilelist[tile];
  const int e  = packed >> 16;
  const int m0 = (packed & 0xffff) * 128;
  const int n0 = (b & 7) * 128;
  const int off = offsets[e];
  const int ne  = offsets[e+1] - off;

  __shared__ unsigned short sA[2][128*32];
  __shared__ unsigned short sB[2][128*32];
  __shared__ int sT[128];

  const int tid  = threadIdx.x;
  const int lane = tid & 63;
  const int wid  = tid >> 6;
  if (tid < 128){
    int r = m0 + tid;
    sT[tid] = (r < ne) ? rowmap[off + r] : 0;
  }

  const int r_in = lane >> 2, seg = lane & 3;
  const int rt0 = wid*32 + r_in;
  const int rt1 = rt0 + 16;
  const int gr0 = off + ((m0 + rt0 < ne) ? (m0 + rt0) : 0);
  const int gr1 = off + ((m0 + rt1 < ne) ? (m0 + rt1) : 0);
  const size_t wbase = (size_t)e * Hd * Id;
  const unsigned short* pA0 = act + (size_t)gr0*Id + seg*8;
  const unsigned short* pA1 = act + (size_t)gr1*Id + seg*8;
  const unsigned short* pB0 = wdb + wbase + (size_t)(n0+rt0)*Id + seg*8;
  const unsigned short* pB1 = wdb + wbase + (size_t)(n0+rt1)*Id + seg*8;
  const int dA0 = wid*1024, dA1 = wid*1024 + 512;

  floatx4 acc[4][4];
  #pragma unroll
  for (int i = 0; i < 4; ++i)
    #pragma unroll
    for (int j = 0; j < 4; ++j){ floatx4 z = {0.f,0.f,0.f,0.f}; acc[i][j] = z; }

  const int wm = (wid & 1) * 64, wn = (wid >> 1) * 64;
  const int fm = lane & 15, fq = lane >> 4;

  load_lds16(pA0, &sA[0][dA0]); load_lds16(pA1, &sA[0][dA1]);
  load_lds16(pB0, &sB[0][dA0]); load_lds16(pB1, &sB[0][dA1]);

  #pragma unroll 2
  for (int kit = 0; kit < 16; ++kit){
    const int cur = kit & 1;
    if (kit < 15){
      const int nk = (kit+1)*32;
      const int nb = 1 - cur;
      load_lds16(pA0 + nk, &sA[nb][dA0]); load_lds16(pA1 + nk, &sA[nb][dA1]);
      load_lds16(pB0 + nk, &sB[nb][dA0]); load_lds16(pB1 + nk, &sB[nb][dA1]);
      WAIT_VM(4);
    } else {
      WAIT_VM(0);
    }
    wg_barrier();
    bf16x8 av[4], bv[4];
    #pragma unroll
    for (int i = 0; i < 4; ++i) av[i] = *(const bf16x8*)(&sA[cur][(wm + i*16 + fm)*32 + fq*8]);
    #pragma unroll
    for (int j = 0; j < 4; ++j) bv[j] = *(const bf16x8*)(&sB[cur][(wn + j*16 + fm)*32 + fq*8]);
    #pragma unroll
    for (int i = 0; i < 4; ++i)
      #pragma unroll
      for (int j = 0; j < 4; ++j)
        acc[i][j] = __builtin_amdgcn_mfma_f32_16x16x32_bf16(av[i], bv[j], acc[i][j], 0, 0, 0);
    wg_barrier();
  }

  #pragma unroll
  for (int i = 0; i < 4; ++i){
    #pragma unroll
    for (int r = 0; r < 4; ++r){
      int row = wm + i*16 + fq*4 + r;
      if (m0 + row < ne){
        int t = sT[row];
        #pragma unroll
        for (int j = 0; j < 4; ++j)
          atomicAdd(&out[(size_t)t*Hd + n0 + wn + j*16 + fm], acc[i][j][r]);
      }
    }
  }
}

// =================================================================
extern "C" void kernel_launch(void* const* d_in, const int* in_sizes, int n_in,
                              void* d_out, int out_size, void* d_ws, size_t ws_size,
                              hipStream_t stream){
  (void)in_sizes; (void)n_in; (void)out_size; (void)ws_size;
  const float* x    = (const float*)d_in[0];
  const float* rw   = (const float*)d_in[1];
  const float* bias = (const float*)d_in[2];
  const float* wg   = (const float*)d_in[3];
  const float* wu   = (const float*)d_in[4];
  const float* wd   = (const float*)d_in[5];
  float* out = (float*)d_out;

  char* ws = (char*)d_ws;
  const size_t WSZ = (size_t)NE * Id * Hd * 2;
  unsigned short* wgb = (unsigned short*)(ws);
  unsigned short* wub = (unsigned short*)(ws + WSZ);
  unsigned short* wdb = (unsigned short*)(ws + 2*WSZ);
  unsigned short* xb  = (unsigned short*)(ws + 3*WSZ);
  unsigned short* act = (unsigned short*)(ws + 3*WSZ + (size_t)T_TOK*Hd*2);
  char* misc = ws + 3*WSZ + (size_t)T_TOK*Hd*2 + (size_t)CAPR*Id*2;

  const size_t LOGB = (size_t)T_TOK * NSLOT * 4;
  float* logits = (float*)misc;
  int*   counts  = (int*)(misc + LOGB);
  int*   cursors = counts + 16;
  int*   offsets = cursors + 16;
  char* p2 = misc + LOGB + 256;
  int*   tkid   = (int*)p2;                         p2 += (size_t)T_TOK*TOPK*4;
  float* tkw    = (float*)p2;                       p2 += (size_t)T_TOK*TOPK*4;
  float* zerow  = (float*)p2;                       p2 += (size_t)T_TOK*4;
  int*   rowmap = (int*)p2;                         p2 += (size_t)CAPR*4;
  float* roww   = (float*)p2;                       p2 += (size_t)CAPR*4;
  int*   tilelist = (int*)p2;                       p2 += (size_t)MAXTILES*4;
  int*   ntiles   = (int*)p2;

  hipMemsetAsync(misc, 0, LOGB + 256, stream);

  cvt_x_kernel<<<T_TOK*Hd/4/256, 256, 0, stream>>>(x, xb);
  transpose_cvt_kernel<<<dim3(Id/64, Hd/64, NE), 256, 0, stream>>>(wg, wgb, Hd, Id);
  transpose_cvt_kernel<<<dim3(Id/64, Hd/64, NE), 256, 0, stream>>>(wu, wub, Hd, Id);
  transpose_cvt_kernel<<<dim3(Hd/64, Id/64, NE), 256, 0, stream>>>(wd, wdb, Id, Hd);

  logits_kernel<<<dim3(T_TOK/128, Hd/256), 256, 0, stream>>>(x, rw, logits);
  topk_kernel<<<T_TOK/256, 256, 0, stream>>>(logits, bias, counts, tkid, tkw, zerow);
  offsets_kernel<<<1, 64, 0, stream>>>(counts, offsets, cursors, tilelist, ntiles);
  build_kernel<<<CAPR/256, 256, 0, stream>>>(tkid, tkw, offsets, cursors, rowmap, roww);

  outinit_kernel<<<T_TOK*Hd/4/256, 256, 0, stream>>>(x, zerow, out);

  gateup_kernel<<<MAXTILES*4, 256, 0, stream>>>(
      xb, wgb, wub, offsets, rowmap, roww, tilelist, ntiles, act);
  down_kernel<<<MAXTILES*8, 256, 0, stream>>>(
      act, wdb, offsets, rowmap, tilelist, ntiles, out);
}